// Round 10
// baseline (581.746 us; speedup 1.0000x reference)
//
#include <hip/hip_runtime.h>
#include <hip/hip_cooperative_groups.h>
#include <math.h>

#define NN 12288      // nodes
#define FD 128        // input feat dim
#define DD 128        // D
#define EE 393216     // edges
#define BB 64         // batch
#define LL 256        // tokens per sample
#define HH 8          // heads
#define DTD 256       // DT = 2*D
#define NTOK 16384    // B*L
#define CAP 128       // max row degree capacity (mean 32)

// k_setup block ranges (scatter moved to cooperative kernel)
#define PROJ_B0 0      // proj MFMA: [0,192)
#define PREP_B0 192    // prep tiles: [192,260)
#define HEUR_B0 260    // heur: [260,324)
#define SBIAS_B 324
#define CLS_B   325
#define SETUP_GRID 326

#define COOP_BLOCKS 1024

// LDS strides in u16 — multiples of 8 (16 B) so every s16x8 access is
// 16-B aligned (ds_*_b128).
#define SEQ_ST 272
#define STG_ST 272

typedef float f32x4 __attribute__((ext_vector_type(4)));
typedef short s16x8 __attribute__((ext_vector_type(8)));

__device__ __forceinline__ float relu_(float x){ return fmaxf(x, 0.0f); }

__device__ __forceinline__ unsigned short f2b(float f){
  unsigned int u = __float_as_uint(f);
  u += 0x7FFFu + ((u >> 16) & 1u);
  return (unsigned short)(u >> 16);
}
__device__ __forceinline__ float b2f(unsigned short h){
  return __uint_as_float(((unsigned int)h) << 16);
}

__device__ __forceinline__ f32x4 MF(s16x8 a, s16x8 b, f32x4 c){
  return __builtin_amdgcn_mfma_f32_16x16x32_bf16(a, b, c, 0, 0, 0);
}

// ---- shared SpMM row body: one wave computes one output row ---------------
__device__ __forceinline__ void spmm_row(int r, int lane,
    const unsigned int* __restrict__ hin32, unsigned int* __restrict__ hout32,
    const int* __restrict__ cnt, const uint2* __restrict__ ccv,
    const unsigned int* __restrict__ featsb32, int finalpass){
  int deg = cnt[r];
  const uint2* base = ccv + (size_t)r*CAP;
  float a0=0.f,a1=0.f,b0=0.f,b1=0.f,c0=0.f,c1=0.f,d0=0.f,d1=0.f;
  int p = 0;
  for(; p+4 <= deg; p += 4){
    uint2 q0 = base[p], q1 = base[p+1], q2 = base[p+2], q3 = base[p+3];
    unsigned u0 = hin32[(size_t)q0.x*64 + lane];
    unsigned u1 = hin32[(size_t)q1.x*64 + lane];
    unsigned u2 = hin32[(size_t)q2.x*64 + lane];
    unsigned u3 = hin32[(size_t)q3.x*64 + lane];
    float v0=__uint_as_float(q0.y), v1=__uint_as_float(q1.y);
    float v2=__uint_as_float(q2.y), v3=__uint_as_float(q3.y);
    a0 += v0*b2f((unsigned short)(u0&0xffffu)); a1 += v0*b2f((unsigned short)(u0>>16));
    b0 += v1*b2f((unsigned short)(u1&0xffffu)); b1 += v1*b2f((unsigned short)(u1>>16));
    c0 += v2*b2f((unsigned short)(u2&0xffffu)); c1 += v2*b2f((unsigned short)(u2>>16));
    d0 += v3*b2f((unsigned short)(u3&0xffffu)); d1 += v3*b2f((unsigned short)(u3>>16));
  }
  for(; p < deg; ++p){
    uint2 q0 = base[p];
    unsigned u0 = hin32[(size_t)q0.x*64 + lane];
    float v0 = __uint_as_float(q0.y);
    a0 += v0*b2f((unsigned short)(u0&0xffffu)); a1 += v0*b2f((unsigned short)(u0>>16));
  }
  a0 += b0 + c0 + d0;
  a1 += b1 + c1 + d1;
  if(finalpass){
    unsigned f = featsb32[(size_t)r*64 + lane];
    a0 = 0.5f*a0 + 0.5f*b2f((unsigned short)(f & 0xffffu));
    a1 = 0.5f*a1 + 0.5f*b2f((unsigned short)(f >> 16));
  }
  hout32[(size_t)r*64 + lane] = (unsigned)f2b(a0) | ((unsigned)f2b(a1) << 16);
}

// ===== cooperative: zero-cnt | scatter | SpMM x3 (2 grid syncs each) =======
__global__ void __launch_bounds__(256, 4)
k_coop(unsigned short* __restrict__ featsb, unsigned short* __restrict__ h1b,
       unsigned short* __restrict__ h2b, unsigned short* __restrict__ rexb,
       int* __restrict__ cnt, uint2* __restrict__ ccv,
       const int* __restrict__ adj_rows, const int* __restrict__ adj_cols,
       const float* __restrict__ adj_vals){
  cooperative_groups::grid_group gg = cooperative_groups::this_grid();
  int t = threadIdx.x, bid = blockIdx.x;
  int gid = bid*256 + t;
  int lane = t & 63, wv = t >> 6;

  if(gid < NN) cnt[gid] = 0;
  gg.sync();

  for(int e = gid; e < EE; e += COOP_BLOCKS*256){
    int r = adj_rows[e];
    int p = atomicAdd(&cnt[r], 1);
    ccv[(size_t)r*CAP + p] = make_uint2((unsigned)adj_cols[e], __float_as_uint(adj_vals[e]));
  }
  gg.sync();

  int r0 = bid*12 + wv*3;   // 1024 blocks * 4 waves * 3 rows = 12288
  #pragma unroll
  for(int i=0;i<3;++i) spmm_row(r0+i, lane, (const unsigned*)featsb, (unsigned*)h1b, cnt, ccv, (const unsigned*)featsb, 0);
  gg.sync();
  #pragma unroll
  for(int i=0;i<3;++i) spmm_row(r0+i, lane, (const unsigned*)h1b, (unsigned*)h2b, cnt, ccv, (const unsigned*)featsb, 0);
  gg.sync();
  #pragma unroll
  for(int i=0;i<3;++i) spmm_row(r0+i, lane, (const unsigned*)h2b, (unsigned*)rexb, cnt, ccv, (const unsigned*)featsb, 1);
}

// ---- fallback standalone kernels (used only if cooperative launch fails) --
__global__ void k_scatter(const int* __restrict__ rows, const int* __restrict__ cols,
                          const float* __restrict__ vals, int* __restrict__ cnt,
                          uint2* __restrict__ ccv){
  int e = blockIdx.x*256 + threadIdx.x;
  int r = rows[e];
  int p = atomicAdd(&cnt[r], 1);
  ccv[(size_t)r*CAP + p] = make_uint2((unsigned)cols[e], __float_as_uint(vals[e]));
}
__global__ void __launch_bounds__(256)
k_spmm_w(const unsigned int* __restrict__ hin32, unsigned int* __restrict__ hout32,
         const int* __restrict__ cnt, const uint2* __restrict__ ccv,
         const unsigned int* __restrict__ featsb32, int finalpass){
  spmm_row(blockIdx.x*4 + (threadIdx.x>>6), threadIdx.x & 63,
           hin32, hout32, cnt, ccv, featsb32, finalpass);
}

// ===== kernel A: proj(MFMA) | prep-tiles | heur | sbias | cls qkv ==========
__global__ void __launch_bounds__(256)
k_setup(const float* __restrict__ x, const float* __restrict__ proj_w,
        const float* __restrict__ proj_b, unsigned short* __restrict__ featsb,
        const float* __restrict__ wq, const float* __restrict__ wk,
        const float* __restrict__ wv,
        const float* __restrict__ enc_w2, const float* __restrict__ sw1,
        const float* __restrict__ sw2, const float* __restrict__ cls_tok,
        unsigned short* __restrict__ wqT, unsigned short* __restrict__ wkT,
        unsigned short* __restrict__ wvT,
        unsigned short* __restrict__ w2T2, unsigned short* __restrict__ w2T3,
        unsigned short* __restrict__ sw1aT, unsigned short* __restrict__ sw1bT,
        unsigned short* __restrict__ sw2T,
        const int* __restrict__ node_idx, const int* __restrict__ srcI,
        const int* __restrict__ dstI, const float* __restrict__ ppr,
        const float* __restrict__ drnl, float* __restrict__ heurA,
        float* __restrict__ heurB, float* __restrict__ heurD,
        const float* __restrict__ enc_b1, const float* __restrict__ enc_b2,
        const float* __restrict__ sb1, float* __restrict__ sbias,
        float* __restrict__ qcls, unsigned short* __restrict__ kcls,
        unsigned short* __restrict__ vcls){
  int t = threadIdx.x;
  if(blockIdx.x < PREP_B0){
    // ---- proj via MFMA ----
    int bid = blockIdx.x - PROJ_B0;
    int row0 = bid * 64;
    int lane = t & 63, w = t >> 6;
    int lr = lane & 15, lg = lane >> 4;
    f32x4 acc[4][2];
    #pragma unroll
    for(int nt=0;nt<2;++nt){
      int col = w*32 + nt*16 + lr;
      float bv = proj_b[col];
      #pragma unroll
      for(int rt=0;rt<4;++rt)
        #pragma unroll
        for(int i=0;i<4;++i) acc[rt][nt][i]=bv;
    }
    #pragma unroll
    for(int ks=0; ks<4; ++ks){
      int kb = ks*32 + lg*8;
      s16x8 Bf[2];
      #pragma unroll
      for(int nt=0;nt<2;++nt){
        int col = w*32 + nt*16 + lr;
        #pragma unroll
        for(int i=0;i<8;++i) Bf[nt][i] = (short)f2b(proj_w[(kb+i)*DD + col]);
      }
      #pragma unroll
      for(int rt=0;rt<4;++rt){
        int row = row0 + rt*16 + lr;
        const f32x4* xp = (const f32x4*)(x + (size_t)row*FD + kb);
        f32x4 v0 = xp[0], v1 = xp[1];
        s16x8 Af;
        #pragma unroll
        for(int i=0;i<4;++i){ Af[i] = (short)f2b(v0[i]); Af[4+i] = (short)f2b(v1[i]); }
        #pragma unroll
        for(int nt=0;nt<2;++nt) acc[rt][nt] = MF(Af, Bf[nt], acc[rt][nt]);
      }
    }
    #pragma unroll
    for(int rt=0;rt<4;++rt)
      #pragma unroll
      for(int nt=0;nt<2;++nt)
        #pragma unroll
        for(int i=0;i<4;++i){
          int row = row0 + rt*16 + lg*4 + i;
          int col = w*32 + nt*16 + lr;
          featsb[(size_t)row*DD + col] = f2b(acc[rt][nt][i]);
        }
  } else if(blockIdx.x < HEUR_B0){
    // ---- prep: LDS-tile transpose to bf16 [out][k] ----
    int bid = blockIdx.x - PREP_B0;
    const float* s; unsigned short* d; int S, k0, n0;
    if(bid < 48){
      int m = bid >> 4, t16 = bid & 15;
      s = (m==0)? wq : (m==1)? wk : wv;
      d = (m==0)? wqT : (m==1)? wkT : wvT;
      S = 256; k0 = (t16>>2)*64; n0 = (t16&3)*64;
    } else {
      int b2 = bid - 48; int m = b2 >> 2, t4 = b2 & 3;
      if(m==0){ s = enc_w2 + 2*16384; d = w2T2; }
      else if(m==1){ s = enc_w2 + 3*16384; d = w2T3; }
      else if(m==2){ s = sw1 + 256*128; d = sw1aT; }
      else if(m==3){ s = sw1 + 384*128; d = sw1bT; }
      else { s = sw2; d = sw2T; }
      S = 128; k0 = (t4>>1)*64; n0 = (t4&1)*64;
    }
    __shared__ unsigned short tile[64][65];
    #pragma unroll
    for(int it=0; it<16; ++it){
      int idx = t + it*256;
      int i = idx>>6, j = idx&63;
      tile[i][j] = f2b(s[(size_t)(k0+i)*S + n0 + j]);
    }
    __syncthreads();
    #pragma unroll
    for(int it=0; it<16; ++it){
      int idx = t + it*256;
      int i2 = idx>>6, j2 = idx&63;
      d[(size_t)(n0+i2)*S + k0 + j2] = tile[j2][i2];
    }
  } else if(blockIdx.x < SBIAS_B){
    // ---- heur gathers ----
    int tt = (blockIdx.x - HEUR_B0)*256 + t;
    int s = tt >> 8;
    int node = node_idx[tt];
    heurA[tt] = ppr[(size_t)srcI[s]*NN + node];
    heurB[tt] = ppr[(size_t)dstI[s]*NN + node];
    heurD[tt] = drnl[(size_t)s*NN + node];
  } else if(blockIdx.x == SBIAS_B){
    // ---- sbias fold ----
    __shared__ float h0[DD], h1[DD], e0[DD], e1[DD];
    if(t < DD){
      h0[t] = relu_(enc_b1[0*DD+t]);
      h1[t] = relu_(enc_b1[1*DD+t]);
    }
    __syncthreads();
    if(t < DD){
      float a0 = enc_b2[0*DD+t], a1 = enc_b2[1*DD+t];
      for(int d2=0; d2<DD; ++d2){
        a0 += h0[d2]*enc_w2[(0*DD+d2)*DD + t];
        a1 += h1[d2]*enc_w2[(1*DD+d2)*DD + t];
      }
      e0[t]=a0; e1[t]=a1;
    }
    __syncthreads();
    if(t < DD){
      float sv = sb1[t];
      for(int d2=0; d2<DD; ++d2)
        sv += e0[d2]*sw1[d2*DD + t] + e1[d2]*sw1[(DD+d2)*DD + t];
      sbias[t]=sv;
    }
  } else {
    // ---- cls q/k/v ----
    __shared__ float scls[DTD];
    scls[t] = cls_tok[t];
    __syncthreads();
    float aq=0.f, ak=0.f, av=0.f;
    for(int d2=0; d2<DTD; ++d2){
      float cv = scls[d2];
      aq += cv*wq[d2*DTD + t];
      ak += cv*wk[d2*DTD + t];
      av += cv*wv[d2*DTD + t];
    }
    qcls[t] = aq;
    kcls[t] = f2b(ak);
    vcls[t] = f2b(av);
  }
}

// ====== fused token MLP + K/V GEMM + Q: 64 tokens/block, 8 waves ===========
__global__ void __launch_bounds__(512)
k_tok_kv(const int* __restrict__ node_idx,
         const float* __restrict__ heurA, const float* __restrict__ heurB,
         const float* __restrict__ heurD,
         const float* __restrict__ enc_w1, const float* __restrict__ enc_b1,
         const unsigned short* __restrict__ w2T2, const unsigned short* __restrict__ w2T3,
         const float* __restrict__ enc_b2,
         const unsigned short* __restrict__ sw1aT, const unsigned short* __restrict__ sw1bT,
         const float* __restrict__ sbias,
         const unsigned short* __restrict__ sw2T, const float* __restrict__ sb2,
         const unsigned short* __restrict__ rexb,
         const unsigned short* __restrict__ wkT, const unsigned short* __restrict__ wvT,
         const unsigned short* __restrict__ wqT,
         unsigned short* __restrict__ kbuf, unsigned short* __restrict__ vbuf,
         float* __restrict__ qbuf){
  __shared__ float sA[64], sB[64], sDV[64];
  __shared__ int sNode[64];
  __shared__ __align__(16) unsigned short hid[64*136];
  __shared__ __align__(16) unsigned short uni[64*STG_ST];
  unsigned short* pe2 = uni;
  unsigned short* pe3 = uni + 64*136;
  unsigned short* seq = uni;
  unsigned short* stg = uni;

  int tid = threadIdx.x;
  int lane = tid & 63;
  int w = tid >> 6;               // 0..7
  int lr = lane & 15;
  int lg = lane >> 4;
  int t0 = blockIdx.x * 64;
  int bs = t0 >> 8;
  int p0 = t0 & 255;

  if(tid < 64){
    int tt = t0 + tid;
    sNode[tid] = node_idx[tt];
    sA[tid]  = heurA[tt];
    sB[tid]  = heurB[tt];
    sDV[tid] = heurD[tt];
  }
  __syncthreads();

  int colm = w*16 + lr;

  // GEMM1: enc2/enc3
  {
    f32x4 acc2[4], acc3[4];
    float b2v = enc_b2[2*DD + colm];
    float b3v = enc_b2[3*DD + colm];
    #pragma unroll
    for(int rt=0;rt<4;++rt)
      #pragma unroll
      for(int i=0;i<4;++i){ acc2[rt][i]=b2v; acc3[rt][i]=b3v; }
    #pragma unroll
    for(int ks=0; ks<4; ++ks){
      int kb = ks*32 + lg*8;
      float w20[8], w21[8], w3s[8], b2c[8], b3c[8];
      #pragma unroll
      for(int i=0;i<8;++i){
        int k = kb + i;
        w20[i] = enc_w1[4*DD + k];
        w21[i] = enc_w1[5*DD + k];
        w3s[i] = enc_w1[6*DD + k] + enc_w1[7*DD + k];
        b2c[i] = enc_b1[2*DD + k];
        b3c[i] = enc_b1[3*DD + k];
      }
      s16x8 B2 = *(const s16x8*)(w2T2 + colm*DD + kb);
      s16x8 B3 = *(const s16x8*)(w2T3 + colm*DD + kb);
      #pragma unroll
      for(int rt=0;rt<4;++rt){
        int row = rt*16 + lr;
        float a = sA[row], b = sB[row], dv = sDV[row];
        s16x8 A2, A3;
        #pragma unroll
        for(int i=0;i<8;++i){
          A2[i] = (short)f2b(relu_(a*w20[i] + b*w21[i] + b2c[i]));
          A3[i] = (short)f2b(relu_(dv*w3s[i] + b3c[i]));
        }
        acc2[rt] = MF(A2, B2, acc2[rt]);
        acc3[rt] = MF(A3, B3, acc3[rt]);
      }
    }
    #pragma unroll
    for(int rt=0;rt<4;++rt)
      #pragma unroll
      for(int i=0;i<4;++i){
        int row = rt*16 + lg*4 + i;
        pe2[row*136 + colm] = f2b(acc2[rt][i]);
        pe3[row*136 + colm] = f2b(acc3[rt][i]);
      }
  }
  __syncthreads();

  // GEMM2: hidden
  {
    f32x4 acc[4];
    float sv = sbias[colm];
    #pragma unroll
    for(int rt=0;rt<4;++rt)
      #pragma unroll
      for(int i=0;i<4;++i) acc[rt][i]=sv;
    #pragma unroll
    for(int ks=0; ks<4; ++ks){
      int kb = ks*32 + lg*8;
      s16x8 Ba = *(const s16x8*)(sw1aT + colm*DD + kb);
      s16x8 Bb = *(const s16x8*)(sw1bT + colm*DD + kb);
      #pragma unroll
      for(int rt=0;rt<4;++rt){
        s16x8 A2 = *(const s16x8*)&pe2[(rt*16+lr)*136 + kb];
        s16x8 A3 = *(const s16x8*)&pe3[(rt*16+lr)*136 + kb];
        acc[rt] = MF(A2, Ba, acc[rt]);
        acc[rt] = MF(A3, Bb, acc[rt]);
      }
    }
    __syncthreads();
    #pragma unroll
    for(int rt=0;rt<4;++rt)
      #pragma unroll
      for(int i=0;i<4;++i){
        int row = rt*16 + lg*4 + i;
        hid[row*136 + colm] = f2b(relu_(acc[rt][i]));
      }
  }
  __syncthreads();

  // GEMM3: struct_out -> seq[:,0:128]; re_x gather -> seq[:,128:256]
  {
    f32x4 acc[4];
    float bv = sb2[colm];
    #pragma unroll
    for(int rt=0;rt<4;++rt)
      #pragma unroll
      for(int i=0;i<4;++i) acc[rt][i]=bv;
    #pragma unroll
    for(int ks=0; ks<4; ++ks){
      int kb = ks*32 + lg*8;
      s16x8 Bc = *(const s16x8*)(sw2T + colm*DD + kb);
      #pragma unroll
      for(int rt=0;rt<4;++rt){
        s16x8 A = *(const s16x8*)&hid[(rt*16+lr)*136 + kb];
        acc[rt] = MF(A, Bc, acc[rt]);
      }
    }
    #pragma unroll
    for(int rt=0;rt<4;++rt)
      #pragma unroll
      for(int i=0;i<4;++i){
        int row = rt*16 + lg*4 + i;
        seq[row*SEQ_ST + colm] = f2b(acc[rt][i]);
      }
    int row = tid >> 3, c = (tid & 7)*16;
    int node = sNode[row];
    const unsigned short* rp = rexb + (size_t)node*DD + c;
    *(s16x8*)(seq + row*SEQ_ST + DD + c)     = *(const s16x8*)(rp);
    *(s16x8*)(seq + row*SEQ_ST + DD + c + 8) = *(const s16x8*)(rp + 8);
  }
  __syncthreads();

  // K,V GEMM from LDS seq (each wave: 32 cols)
  f32x4 accK[4][2], accV[4][2];
  {
    #pragma unroll
    for(int rt=0;rt<4;++rt)
      #pragma unroll
      for(int nt=0;nt<2;++nt)
        #pragma unroll
        for(int i=0;i<4;++i){ accK[rt][nt][i]=0.f; accV[rt][nt][i]=0.f; }
    int col0 = w * 32;
    #pragma unroll
    for(int ks=0; ks<8; ++ks){
      int kb = ks*32 + lg*8;
      s16x8 A[4], Bk[2], Bv[2];
      #pragma unroll
      for(int rt=0;rt<4;++rt)
        A[rt] = *(const s16x8*)&seq[(rt*16+lr)*SEQ_ST + kb];
      #pragma unroll
      for(int nt=0;nt<2;++nt){
        int col = col0 + nt*16 + lr;
        Bk[nt] = *(const s16x8*)(wkT + (size_t)col*DTD + kb);
        Bv[nt] = *(const s16x8*)(wvT + (size_t)col*DTD + kb);
      }
      #pragma unroll
      for(int rt=0;rt<4;++rt)
        #pragma unroll
        for(int nt=0;nt<2;++nt){
          accK[rt][nt] = MF(A[rt], Bk[nt], accK[rt][nt]);
          accV[rt][nt] = MF(A[rt], Bv[nt], accV[rt][nt]);
        }
    }
  }
  if(p0 == 0){
    int qi = tid >> 8, col = tid & 255;
    float acc = 0.f;
    for(int d=0; d<DTD; d+=8){
      s16x8 wv8 = *(const s16x8*)(wqT + (size_t)col*DTD + d);
      #pragma unroll
      for(int j=0;j<8;++j)
        acc += b2f(seq[qi*SEQ_ST + d + j]) * b2f((unsigned short)wv8[j]);
    }
    qbuf[(size_t)(bs*2+qi)*DTD + col] = acc;
  }
  __syncthreads();

  // stage K -> coalesced store
  {
    int col0 = w * 32;
    #pragma unroll
    for(int rt=0;rt<4;++rt)
      #pragma unroll
      for(int nt=0;nt<2;++nt)
        #pragma unroll
        for(int i=0;i<4;++i)
          stg[(rt*16 + lg*4 + i)*STG_ST + col0 + nt*16 + lr] = f2b(accK[rt][nt][i]);
  }
  __syncthreads();
  {
    int row = tid >> 3, c = (tid & 7)*32;
    #pragma unroll
    for(int j=0;j<4;++j)
      *(s16x8*)(kbuf + (size_t)(t0+row)*DTD + c + j*8) = *(const s16x8*)&stg[row*STG_ST + c + j*8];
  }
  __syncthreads();
  {
    int col0 = w * 32;
    #pragma unroll
    for(int rt=0;rt<4;++rt)
      #pragma unroll
      for(int nt=0;nt<2;++nt)
        #pragma unroll
        for(int i=0;i<4;++i)
          stg[(rt*16 + lg*4 + i)*STG_ST + col0 + nt*16 + lr] = f2b(accV[rt][nt][i]);
  }
  __syncthreads();
  {
    int row = tid >> 3, c = (tid & 7)*32;
    #pragma unroll
    for(int j=0;j<4;++j)
      *(s16x8*)(vbuf + (size_t)(t0+row)*DTD + c + j*8) = *(const s16x8*)&stg[row*STG_ST + c + j*8];
  }
}

// ====== fused attention + output: one block per (b,qi), 192 blocks =========
__global__ void __launch_bounds__(256)
k_att_out(const float* __restrict__ qcls, const float* __restrict__ qbuf,
          const unsigned short* __restrict__ kcls, const unsigned short* __restrict__ vcls,
          const unsigned short* __restrict__ kbuf, const unsigned short* __restrict__ vbuf,
          const float* __restrict__ wo, float* __restrict__ out){
  __shared__ float q_s[DTD];
  __shared__ float sc[HH][257];
  __shared__ float ao[DTD];
  int t = threadIdx.x;
  int b = blockIdx.x / 3, qi = blockIdx.x - b*3;

  q_s[t] = (qi==0) ? qcls[t] : qbuf[(size_t)(b*2+qi-1)*DTD + t];
  __syncthreads();
  const float scale = 0.17677669529663687f;  // 1/sqrt(32)
  for(int kk=t; kk<257; kk+=256){
    const unsigned short* kr = (kk==0) ? kcls : (kbuf + (size_t)(b*256+kk-1)*DTD);
    float acc[HH];
    #pragma unroll
    for(int h=0;h<HH;++h) acc[h]=0.f;
    #pragma unroll
    for(int j=0;j<32;++j){
      s16x8 u = *(const s16x8*)(kr + j*8);
      float p = 0.f;
      #pragma unroll
      for(int m=0;m<8;++m) p += q_s[j*8+m]*b2f((unsigned short)u[m]);
      acc[j>>2] += p;
    }
    #pragma unroll
    for(int h=0;h<HH;++h) sc[h][kk] = acc[h]*scale;
  }
  __syncthreads();
  { // softmax: 4 waves x 2 heads
    int wv = t>>6, lane = t&63;
    #pragma unroll
    for(int j=0;j<2;++j){
      int h = wv*2 + j;
      float x0=sc[h][lane], x1=sc[h][lane+64], x2=sc[h][lane+128], x3=sc[h][lane+192];
      float x4 = (lane==0)? sc[h][256] : -1e30f;
      float m = fmaxf(fmaxf(fmaxf(x0,x1),fmaxf(x2,x3)),x4);
      #pragma unroll
      for(int off=32; off>0; off>>=1) m = fmaxf(m, __shfl_xor(m, off));
      float e0=expf(x0-m), e1=expf(x1-m), e2v=expf(x2-m), e3v=expf(x3-m);
      float e4=(lane==0)? expf(x4-m) : 0.f;
      float s = e0+e1+e2v+e3v+e4;
      #pragma unroll
      for(int off=32; off>0; off>>=1) s += __shfl_xor(s, off);
      float inv = 1.0f/s;
      sc[h][lane]=e0*inv; sc[h][lane+64]=e1*inv;
      sc[h][lane+128]=e2v*inv; sc[h][lane+192]=e3v*inv;
      if(lane==0) sc[h][256]=e4*inv;
    }
  }
  __syncthreads();
  { // PV: thread = (h,dd); kk=0 cls then 256 tokens (4 partial accums)
    int h = t>>5, dd = t&31;
    float a0 = sc[h][0]*b2f(vcls[h*32+dd]);
    float a1=0.f, a2=0.f, a3=0.f;
    const unsigned short* vb = vbuf + (size_t)b*256*DTD + h*32 + dd;
    for(int kk=1; kk<257; kk+=4){
      a0 += sc[h][kk]  *b2f(vb[(size_t)(kk-1)*DTD]);
      a1 += sc[h][kk+1]*b2f(vb[(size_t)(kk)*DTD]);
      a2 += sc[h][kk+2]*b2f(vb[(size_t)(kk+1)*DTD]);
      a3 += sc[h][kk+3]*b2f(vb[(size_t)(kk+2)*DTD]);
    }
    ao[t] = a0+a1+a2+a3;
  }
  __syncthreads();
  { // out row = ao @ wo
    float acc = 0.f;
    for(int d=0; d<DTD; ++d) acc += ao[d]*wo[d*DTD + t];
    int off = (qi==1)? 0 : ((qi==2)? DTD : 2*DTD);
    out[(size_t)b*768 + off + t] = acc;
  }
}

extern "C" void kernel_launch(void* const* d_in, const int* in_sizes, int n_in,
                              void* d_out, int out_size, void* d_ws, size_t ws_size,
                              hipStream_t stream){
  const float* x        = (const float*)d_in[0];
  const float* proj_w   = (const float*)d_in[1];
  const float* proj_b   = (const float*)d_in[2];
  const float* adj_vals = (const float*)d_in[3];
  const int*   adj_rows = (const int*)d_in[4];
  const int*   adj_cols = (const int*)d_in[5];
  const float* ppr      = (const float*)d_in[6];
  const float* drnl     = (const float*)d_in[7];
  const int*   srcI     = (const int*)d_in[8];
  const int*   dstI     = (const int*)d_in[9];
  const int*   node_idx   = (const int*)d_in[11];
  const float* enc_w1   = (const float*)d_in[12];
  const float* enc_b1   = (const float*)d_in[13];
  const float* enc_w2   = (const float*)d_in[14];
  const float* enc_b2   = (const float*)d_in[15];
  const float* sw1      = (const float*)d_in[16];
  const float* sb1      = (const float*)d_in[17];
  const float* sw2      = (const float*)d_in[18];
  const float* sb2      = (const float*)d_in[19];
  const float* cls_tok  = (const float*)d_in[20];
  const float* wq       = (const float*)d_in[21];
  const float* wk       = (const float*)d_in[22];
  const float* wv       = (const float*)d_in[23];
  const float* wo       = (const float*)d_in[24];
  float* out = (float*)d_out;

  char* p = (char*)d_ws;
  auto alloc = [&](size_t bytes)->void*{ void* r = (void*)p; p += (bytes + 63) & ~(size_t)63; return r; };
  unsigned short* featsb = (unsigned short*)alloc((size_t)NN*DD*2);
  unsigned short* h1b    = (unsigned short*)alloc((size_t)NN*DD*2);
  unsigned short* h2b    = (unsigned short*)alloc((size_t)NN*DD*2);
  unsigned short* rexb   = (unsigned short*)alloc((size_t)NN*DD*2);
  int*   cnt     = (int*)  alloc((size_t)NN*4);
  uint2* ccv     = (uint2*)alloc((size_t)NN*CAP*8);
  float* sbias   = (float*)alloc((size_t)DD*4);
  float* heurA   = (float*)alloc((size_t)NTOK*4);
  float* heurB   = (float*)alloc((size_t)NTOK*4);
  float* heurD   = (float*)alloc((size_t)NTOK*4);
  unsigned short* kbuf = (unsigned short*)alloc((size_t)NTOK*DTD*2);
  unsigned short* vbuf = (unsigned short*)alloc((size_t)NTOK*DTD*2);
  float* qbuf    = (float*)alloc((size_t)BB*2*DTD*4);
  float* qcls    = (float*)alloc((size_t)DTD*4);
  unsigned short* kcls = (unsigned short*)alloc((size_t)DTD*2);
  unsigned short* vcls = (unsigned short*)alloc((size_t)DTD*2);
  unsigned short* wqT   = (unsigned short*)alloc((size_t)DTD*DTD*2);
  unsigned short* wkT   = (unsigned short*)alloc((size_t)DTD*DTD*2);
  unsigned short* wvT   = (unsigned short*)alloc((size_t)DTD*DTD*2);
  unsigned short* w2T2  = (unsigned short*)alloc((size_t)DD*DD*2);
  unsigned short* w2T3  = (unsigned short*)alloc((size_t)DD*DD*2);
  unsigned short* sw1aT = (unsigned short*)alloc((size_t)DD*DD*2);
  unsigned short* sw1bT = (unsigned short*)alloc((size_t)DD*DD*2);
  unsigned short* sw2T  = (unsigned short*)alloc((size_t)DD*DD*2);

  k_setup  <<<SETUP_GRID, 256, 0, stream>>>(x, proj_w, proj_b, featsb,
                                            wq, wk, wv, enc_w2, sw1, sw2, cls_tok,
                                            wqT, wkT, wvT, w2T2, w2T3, sw1aT, sw1bT, sw2T,
                                            node_idx, srcI, dstI, ppr, drnl,
                                            heurA, heurB, heurD,
                                            enc_b1, enc_b2, sb1, sbias,
                                            qcls, kcls, vcls);

  // cooperative: zero-cnt | scatter | 3x SpMM (grid syncs inside)
  {
    unsigned short *a0=featsb, *a1=h1b, *a2=h2b, *a3=rexb;
    int* a4 = cnt; uint2* a5 = ccv;
    const int* a6 = adj_rows; const int* a7 = adj_cols; const float* a8 = adj_vals;
    void* args[] = {&a0,&a1,&a2,&a3,&a4,&a5,&a6,&a7,&a8};
    hipError_t err = hipLaunchCooperativeKernel((const void*)k_coop,
                       dim3(COOP_BLOCKS), dim3(256), args, 0, stream);
    if(err != hipSuccess){
      // fallback: classic 5-dispatch path
      hipMemsetAsync(cnt, 0, NN*sizeof(int), stream);
      k_scatter<<<EE/256, 256, 0, stream>>>(adj_rows, adj_cols, adj_vals, cnt, ccv);
      k_spmm_w <<<NN/4,   256, 0, stream>>>((const unsigned*)featsb, (unsigned*)h1b, cnt, ccv, (const unsigned*)featsb, 0);
      k_spmm_w <<<NN/4,   256, 0, stream>>>((const unsigned*)h1b, (unsigned*)h2b, cnt, ccv, (const unsigned*)featsb, 0);
      k_spmm_w <<<NN/4,   256, 0, stream>>>((const unsigned*)h2b, (unsigned*)rexb, cnt, ccv, (const unsigned*)featsb, 1);
    }
  }

  k_tok_kv <<<NTOK/64, 512, 0, stream>>>(node_idx, heurA, heurB, heurD,
                                         enc_w1, enc_b1, w2T2, w2T3, enc_b2,
                                         sw1aT, sw1bT, sbias, sw2T, sb2, rexb,
                                         wkT, wvT, wqT, kbuf, vbuf, qbuf);
  k_att_out<<<BB*3,    256, 0, stream>>>(qcls, qbuf, kcls, vcls, kbuf, vbuf, wo, out);
}

// Round 11
// 154.013 us; speedup vs baseline: 3.7772x; 3.7772x over previous
//
#include <hip/hip_runtime.h>
#include <math.h>

#define NN 12288      // nodes
#define FD 128        // input feat dim
#define DD 128        // D
#define EE 393216     // edges
#define BB 64         // batch
#define LL 256        // tokens per sample
#define HH 8          // heads
#define DTD 256       // DT = 2*D
#define NTOK 16384    // B*L
#define CAP 128       // max row degree capacity (mean 32)

// k_setup block ranges
#define PROJ_B0 1536   // scatter: [0,1536)
#define PREP_B0 1728   // proj MFMA: [1536,1728)
#define HEUR_B0 1796   // prep tiles: [1728,1796)
#define SBIAS_B 1860   // heur: [1796,1860); sbias: 1860; cls: 1861
#define CLS_B   1861
#define SETUP_GRID 1862

// LDS strides in u16 — multiples of 8 (16 B) so every s16x8 access is
// 16-B aligned (ds_*_b128).
#define SEQ_ST 272
#define STG_ST 272

typedef float f32x4 __attribute__((ext_vector_type(4)));
typedef short s16x8 __attribute__((ext_vector_type(8)));

__device__ __forceinline__ float relu_(float x){ return fmaxf(x, 0.0f); }

__device__ __forceinline__ unsigned short f2b(float f){
  unsigned int u = __float_as_uint(f);
  u += 0x7FFFu + ((u >> 16) & 1u);
  return (unsigned short)(u >> 16);
}
__device__ __forceinline__ float b2f(unsigned short h){
  return __uint_as_float(((unsigned int)h) << 16);
}

__device__ __forceinline__ f32x4 MF(s16x8 a, s16x8 b, f32x4 c){
  return __builtin_amdgcn_mfma_f32_16x16x32_bf16(a, b, c, 0, 0, 0);
}

// ===== kernel A: scatter | proj(MFMA) | prep-tiles | heur | sbias | cls =====
__global__ void __launch_bounds__(256)
k_setup(const float* __restrict__ x, const float* __restrict__ proj_w,
        const float* __restrict__ proj_b, unsigned short* __restrict__ featsb,
        const float* __restrict__ wq, const float* __restrict__ wk,
        const float* __restrict__ wv,
        const float* __restrict__ enc_w2, const float* __restrict__ sw1,
        const float* __restrict__ sw2, const float* __restrict__ cls_tok,
        unsigned short* __restrict__ wqT, unsigned short* __restrict__ wkT,
        unsigned short* __restrict__ wvT,
        unsigned short* __restrict__ w2T2, unsigned short* __restrict__ w2T3,
        unsigned short* __restrict__ sw1aT, unsigned short* __restrict__ sw1bT,
        unsigned short* __restrict__ sw2T,
        const int* __restrict__ node_idx, const int* __restrict__ srcI,
        const int* __restrict__ dstI, const float* __restrict__ ppr,
        const float* __restrict__ drnl, float* __restrict__ heurA,
        float* __restrict__ heurB, float* __restrict__ heurD,
        const int* __restrict__ adj_rows, const int* __restrict__ adj_cols,
        const float* __restrict__ adj_vals, int* __restrict__ cnt,
        uint2* __restrict__ ccv,
        const float* __restrict__ enc_b1, const float* __restrict__ enc_b2,
        const float* __restrict__ sb1, float* __restrict__ sbias,
        float* __restrict__ qcls, unsigned short* __restrict__ kcls,
        unsigned short* __restrict__ vcls){
  int t = threadIdx.x;
  if(blockIdx.x < PROJ_B0){
    // ---- scatter: bump-allocate edges into row buckets ----
    int e = blockIdx.x*256 + t;
    int r = adj_rows[e];
    int p = atomicAdd(&cnt[r], 1);
    ccv[(size_t)r*CAP + p] = make_uint2((unsigned)adj_cols[e], __float_as_uint(adj_vals[e]));
  } else if(blockIdx.x < PREP_B0){
    // ---- proj via MFMA ----
    int bid = blockIdx.x - PROJ_B0;
    int row0 = bid * 64;
    int lane = t & 63, w = t >> 6;
    int lr = lane & 15, lg = lane >> 4;
    f32x4 acc[4][2];
    #pragma unroll
    for(int nt=0;nt<2;++nt){
      int col = w*32 + nt*16 + lr;
      float bv = proj_b[col];
      #pragma unroll
      for(int rt=0;rt<4;++rt)
        #pragma unroll
        for(int i=0;i<4;++i) acc[rt][nt][i]=bv;
    }
    #pragma unroll
    for(int ks=0; ks<4; ++ks){
      int kb = ks*32 + lg*8;
      s16x8 Bf[2];
      #pragma unroll
      for(int nt=0;nt<2;++nt){
        int col = w*32 + nt*16 + lr;
        #pragma unroll
        for(int i=0;i<8;++i) Bf[nt][i] = (short)f2b(proj_w[(kb+i)*DD + col]);
      }
      #pragma unroll
      for(int rt=0;rt<4;++rt){
        int row = row0 + rt*16 + lr;
        const f32x4* xp = (const f32x4*)(x + (size_t)row*FD + kb);
        f32x4 v0 = xp[0], v1 = xp[1];
        s16x8 Af;
        #pragma unroll
        for(int i=0;i<4;++i){ Af[i] = (short)f2b(v0[i]); Af[4+i] = (short)f2b(v1[i]); }
        #pragma unroll
        for(int nt=0;nt<2;++nt) acc[rt][nt] = MF(Af, Bf[nt], acc[rt][nt]);
      }
    }
    #pragma unroll
    for(int rt=0;rt<4;++rt)
      #pragma unroll
      for(int nt=0;nt<2;++nt)
        #pragma unroll
        for(int i=0;i<4;++i){
          int row = row0 + rt*16 + lg*4 + i;
          int col = w*32 + nt*16 + lr;
          featsb[(size_t)row*DD + col] = f2b(acc[rt][nt][i]);
        }
  } else if(blockIdx.x < HEUR_B0){
    // ---- prep: LDS-tile transpose to bf16 [out][k] ----
    int bid = blockIdx.x - PREP_B0;
    const float* s; unsigned short* d; int S, k0, n0;
    if(bid < 48){
      int m = bid >> 4, t16 = bid & 15;
      s = (m==0)? wq : (m==1)? wk : wv;
      d = (m==0)? wqT : (m==1)? wkT : wvT;
      S = 256; k0 = (t16>>2)*64; n0 = (t16&3)*64;
    } else {
      int b2 = bid - 48; int m = b2 >> 2, t4 = b2 & 3;
      if(m==0){ s = enc_w2 + 2*16384; d = w2T2; }
      else if(m==1){ s = enc_w2 + 3*16384; d = w2T3; }
      else if(m==2){ s = sw1 + 256*128; d = sw1aT; }
      else if(m==3){ s = sw1 + 384*128; d = sw1bT; }
      else { s = sw2; d = sw2T; }
      S = 128; k0 = (t4>>1)*64; n0 = (t4&1)*64;
    }
    __shared__ unsigned short tile[64][65];
    #pragma unroll
    for(int it=0; it<16; ++it){
      int idx = t + it*256;
      int i = idx>>6, j = idx&63;
      tile[i][j] = f2b(s[(size_t)(k0+i)*S + n0 + j]);
    }
    __syncthreads();
    #pragma unroll
    for(int it=0; it<16; ++it){
      int idx = t + it*256;
      int i2 = idx>>6, j2 = idx&63;
      d[(size_t)(n0+i2)*S + k0 + j2] = tile[j2][i2];
    }
  } else if(blockIdx.x < SBIAS_B){
    // ---- heur gathers ----
    int tt = (blockIdx.x - HEUR_B0)*256 + t;
    int s = tt >> 8;
    int node = node_idx[tt];
    heurA[tt] = ppr[(size_t)srcI[s]*NN + node];
    heurB[tt] = ppr[(size_t)dstI[s]*NN + node];
    heurD[tt] = drnl[(size_t)s*NN + node];
  } else if(blockIdx.x == SBIAS_B){
    // ---- sbias fold ----
    __shared__ float h0[DD], h1[DD], e0[DD], e1[DD];
    if(t < DD){
      h0[t] = relu_(enc_b1[0*DD+t]);
      h1[t] = relu_(enc_b1[1*DD+t]);
    }
    __syncthreads();
    if(t < DD){
      float a0 = enc_b2[0*DD+t], a1 = enc_b2[1*DD+t];
      for(int d2=0; d2<DD; ++d2){
        a0 += h0[d2]*enc_w2[(0*DD+d2)*DD + t];
        a1 += h1[d2]*enc_w2[(1*DD+d2)*DD + t];
      }
      e0[t]=a0; e1[t]=a1;
    }
    __syncthreads();
    if(t < DD){
      float sv = sb1[t];
      for(int d2=0; d2<DD; ++d2)
        sv += e0[d2]*sw1[d2*DD + t] + e1[d2]*sw1[(DD+d2)*DD + t];
      sbias[t]=sv;
    }
  } else {
    // ---- cls q/k/v ----
    __shared__ float scls[DTD];
    scls[t] = cls_tok[t];
    __syncthreads();
    float aq=0.f, ak=0.f, av=0.f;
    for(int d2=0; d2<DTD; ++d2){
      float cv = scls[d2];
      aq += cv*wq[d2*DTD + t];
      ak += cv*wk[d2*DTD + t];
      av += cv*wv[d2*DTD + t];
    }
    qcls[t] = aq;
    kcls[t] = f2b(ak);
    vcls[t] = f2b(av);
  }
}

// ============ pull SpMM: one wave per row, unroll-4, bucketed CSR ==========
__global__ void __launch_bounds__(256)
k_spmm_w(const unsigned int* __restrict__ hin32, unsigned int* __restrict__ hout32,
         const int* __restrict__ cnt, const uint2* __restrict__ ccv,
         const unsigned int* __restrict__ featsb32, int finalpass){
  int lane = threadIdx.x & 63;
  int r = blockIdx.x*4 + (threadIdx.x>>6);
  int deg = cnt[r];
  const uint2* base = ccv + (size_t)r*CAP;
  float a0=0.f,a1=0.f,b0=0.f,b1=0.f,c0=0.f,c1=0.f,d0=0.f,d1=0.f;
  int p = 0;
  for(; p+4 <= deg; p += 4){
    uint2 q0 = base[p], q1 = base[p+1], q2 = base[p+2], q3 = base[p+3];
    unsigned u0 = hin32[(size_t)q0.x*64 + lane];
    unsigned u1 = hin32[(size_t)q1.x*64 + lane];
    unsigned u2 = hin32[(size_t)q2.x*64 + lane];
    unsigned u3 = hin32[(size_t)q3.x*64 + lane];
    float v0=__uint_as_float(q0.y), v1=__uint_as_float(q1.y);
    float v2=__uint_as_float(q2.y), v3=__uint_as_float(q3.y);
    a0 += v0*b2f((unsigned short)(u0&0xffffu)); a1 += v0*b2f((unsigned short)(u0>>16));
    b0 += v1*b2f((unsigned short)(u1&0xffffu)); b1 += v1*b2f((unsigned short)(u1>>16));
    c0 += v2*b2f((unsigned short)(u2&0xffffu)); c1 += v2*b2f((unsigned short)(u2>>16));
    d0 += v3*b2f((unsigned short)(u3&0xffffu)); d1 += v3*b2f((unsigned short)(u3>>16));
  }
  for(; p < deg; ++p){
    uint2 q0 = base[p];
    unsigned u0 = hin32[(size_t)q0.x*64 + lane];
    float v0 = __uint_as_float(q0.y);
    a0 += v0*b2f((unsigned short)(u0&0xffffu)); a1 += v0*b2f((unsigned short)(u0>>16));
  }
  a0 += b0 + c0 + d0;
  a1 += b1 + c1 + d1;
  if(finalpass){
    unsigned f = featsb32[(size_t)r*64 + lane];
    a0 = 0.5f*a0 + 0.5f*b2f((unsigned short)(f & 0xffffu));
    a1 = 0.5f*a1 + 0.5f*b2f((unsigned short)(f >> 16));
  }
  hout32[(size_t)r*64 + lane] = (unsigned)f2b(a0) | ((unsigned)f2b(a1) << 16);
}

// ====== fused token MLP + K/V GEMM + Q: 64 tokens/block, 8 waves ===========
__global__ void __launch_bounds__(512)
k_tok_kv(const int* __restrict__ node_idx,
         const float* __restrict__ heurA, const float* __restrict__ heurB,
         const float* __restrict__ heurD,
         const float* __restrict__ enc_w1, const float* __restrict__ enc_b1,
         const unsigned short* __restrict__ w2T2, const unsigned short* __restrict__ w2T3,
         const float* __restrict__ enc_b2,
         const unsigned short* __restrict__ sw1aT, const unsigned short* __restrict__ sw1bT,
         const float* __restrict__ sbias,
         const unsigned short* __restrict__ sw2T, const float* __restrict__ sb2,
         const unsigned short* __restrict__ rexb,
         const unsigned short* __restrict__ wkT, const unsigned short* __restrict__ wvT,
         const unsigned short* __restrict__ wqT,
         unsigned short* __restrict__ kbuf, unsigned short* __restrict__ vbuf,
         float* __restrict__ qbuf){
  __shared__ float sA[64], sB[64], sDV[64];
  __shared__ int sNode[64];
  __shared__ __align__(16) unsigned short hid[64*136];
  __shared__ __align__(16) unsigned short uni[64*STG_ST];
  unsigned short* pe2 = uni;
  unsigned short* pe3 = uni + 64*136;
  unsigned short* seq = uni;
  unsigned short* stg = uni;

  int tid = threadIdx.x;
  int lane = tid & 63;
  int w = tid >> 6;               // 0..7
  int lr = lane & 15;
  int lg = lane >> 4;
  int t0 = blockIdx.x * 64;
  int bs = t0 >> 8;
  int p0 = t0 & 255;

  if(tid < 64){
    int tt = t0 + tid;
    sNode[tid] = node_idx[tt];
    sA[tid]  = heurA[tt];
    sB[tid]  = heurB[tt];
    sDV[tid] = heurD[tt];
  }
  __syncthreads();

  int colm = w*16 + lr;

  // GEMM1: enc2/enc3
  {
    f32x4 acc2[4], acc3[4];
    float b2v = enc_b2[2*DD + colm];
    float b3v = enc_b2[3*DD + colm];
    #pragma unroll
    for(int rt=0;rt<4;++rt)
      #pragma unroll
      for(int i=0;i<4;++i){ acc2[rt][i]=b2v; acc3[rt][i]=b3v; }
    #pragma unroll
    for(int ks=0; ks<4; ++ks){
      int kb = ks*32 + lg*8;
      float w20[8], w21[8], w3s[8], b2c[8], b3c[8];
      #pragma unroll
      for(int i=0;i<8;++i){
        int k = kb + i;
        w20[i] = enc_w1[4*DD + k];
        w21[i] = enc_w1[5*DD + k];
        w3s[i] = enc_w1[6*DD + k] + enc_w1[7*DD + k];
        b2c[i] = enc_b1[2*DD + k];
        b3c[i] = enc_b1[3*DD + k];
      }
      s16x8 B2 = *(const s16x8*)(w2T2 + colm*DD + kb);
      s16x8 B3 = *(const s16x8*)(w2T3 + colm*DD + kb);
      #pragma unroll
      for(int rt=0;rt<4;++rt){
        int row = rt*16 + lr;
        float a = sA[row], b = sB[row], dv = sDV[row];
        s16x8 A2, A3;
        #pragma unroll
        for(int i=0;i<8;++i){
          A2[i] = (short)f2b(relu_(a*w20[i] + b*w21[i] + b2c[i]));
          A3[i] = (short)f2b(relu_(dv*w3s[i] + b3c[i]));
        }
        acc2[rt] = MF(A2, B2, acc2[rt]);
        acc3[rt] = MF(A3, B3, acc3[rt]);
      }
    }
    #pragma unroll
    for(int rt=0;rt<4;++rt)
      #pragma unroll
      for(int i=0;i<4;++i){
        int row = rt*16 + lg*4 + i;
        pe2[row*136 + colm] = f2b(acc2[rt][i]);
        pe3[row*136 + colm] = f2b(acc3[rt][i]);
      }
  }
  __syncthreads();

  // GEMM2: hidden
  {
    f32x4 acc[4];
    float sv = sbias[colm];
    #pragma unroll
    for(int rt=0;rt<4;++rt)
      #pragma unroll
      for(int i=0;i<4;++i) acc[rt][i]=sv;
    #pragma unroll
    for(int ks=0; ks<4; ++ks){
      int kb = ks*32 + lg*8;
      s16x8 Ba = *(const s16x8*)(sw1aT + colm*DD + kb);
      s16x8 Bb = *(const s16x8*)(sw1bT + colm*DD + kb);
      #pragma unroll
      for(int rt=0;rt<4;++rt){
        s16x8 A2 = *(const s16x8*)&pe2[(rt*16+lr)*136 + kb];
        s16x8 A3 = *(const s16x8*)&pe3[(rt*16+lr)*136 + kb];
        acc[rt] = MF(A2, Ba, acc[rt]);
        acc[rt] = MF(A3, Bb, acc[rt]);
      }
    }
    __syncthreads();
    #pragma unroll
    for(int rt=0;rt<4;++rt)
      #pragma unroll
      for(int i=0;i<4;++i){
        int row = rt*16 + lg*4 + i;
        hid[row*136 + colm] = f2b(relu_(acc[rt][i]));
      }
  }
  __syncthreads();

  // GEMM3: struct_out -> seq[:,0:128]; re_x gather -> seq[:,128:256]
  {
    f32x4 acc[4];
    float bv = sb2[colm];
    #pragma unroll
    for(int rt=0;rt<4;++rt)
      #pragma unroll
      for(int i=0;i<4;++i) acc[rt][i]=bv;
    #pragma unroll
    for(int ks=0; ks<4; ++ks){
      int kb = ks*32 + lg*8;
      s16x8 Bc = *(const s16x8*)(sw2T + colm*DD + kb);
      #pragma unroll
      for(int rt=0;rt<4;++rt){
        s16x8 A = *(const s16x8*)&hid[(rt*16+lr)*136 + kb];
        acc[rt] = MF(A, Bc, acc[rt]);
      }
    }
    #pragma unroll
    for(int rt=0;rt<4;++rt)
      #pragma unroll
      for(int i=0;i<4;++i){
        int row = rt*16 + lg*4 + i;
        seq[row*SEQ_ST + colm] = f2b(acc[rt][i]);
      }
    int row = tid >> 3, c = (tid & 7)*16;
    int node = sNode[row];
    const unsigned short* rp = rexb + (size_t)node*DD + c;
    *(s16x8*)(seq + row*SEQ_ST + DD + c)     = *(const s16x8*)(rp);
    *(s16x8*)(seq + row*SEQ_ST + DD + c + 8) = *(const s16x8*)(rp + 8);
  }
  __syncthreads();

  // K,V GEMM from LDS seq (each wave: 32 cols)
  f32x4 accK[4][2], accV[4][2];
  {
    #pragma unroll
    for(int rt=0;rt<4;++rt)
      #pragma unroll
      for(int nt=0;nt<2;++nt)
        #pragma unroll
        for(int i=0;i<4;++i){ accK[rt][nt][i]=0.f; accV[rt][nt][i]=0.f; }
    int col0 = w * 32;
    #pragma unroll
    for(int ks=0; ks<8; ++ks){
      int kb = ks*32 + lg*8;
      s16x8 A[4], Bk[2], Bv[2];
      #pragma unroll
      for(int rt=0;rt<4;++rt)
        A[rt] = *(const s16x8*)&seq[(rt*16+lr)*SEQ_ST + kb];
      #pragma unroll
      for(int nt=0;nt<2;++nt){
        int col = col0 + nt*16 + lr;
        Bk[nt] = *(const s16x8*)(wkT + (size_t)col*DTD + kb);
        Bv[nt] = *(const s16x8*)(wvT + (size_t)col*DTD + kb);
      }
      #pragma unroll
      for(int rt=0;rt<4;++rt)
        #pragma unroll
        for(int nt=0;nt<2;++nt){
          accK[rt][nt] = MF(A[rt], Bk[nt], accK[rt][nt]);
          accV[rt][nt] = MF(A[rt], Bv[nt], accV[rt][nt]);
        }
    }
  }
  if(p0 == 0){
    int qi = tid >> 8, col = tid & 255;
    float acc = 0.f;
    for(int d=0; d<DTD; d+=8){
      s16x8 wv8 = *(const s16x8*)(wqT + (size_t)col*DTD + d);
      #pragma unroll
      for(int j=0;j<8;++j)
        acc += b2f(seq[qi*SEQ_ST + d + j]) * b2f((unsigned short)wv8[j]);
    }
    qbuf[(size_t)(bs*2+qi)*DTD + col] = acc;
  }
  __syncthreads();

  // stage K -> coalesced store
  {
    int col0 = w * 32;
    #pragma unroll
    for(int rt=0;rt<4;++rt)
      #pragma unroll
      for(int nt=0;nt<2;++nt)
        #pragma unroll
        for(int i=0;i<4;++i)
          stg[(rt*16 + lg*4 + i)*STG_ST + col0 + nt*16 + lr] = f2b(accK[rt][nt][i]);
  }
  __syncthreads();
  {
    int row = tid >> 3, c = (tid & 7)*32;
    #pragma unroll
    for(int j=0;j<4;++j)
      *(s16x8*)(kbuf + (size_t)(t0+row)*DTD + c + j*8) = *(const s16x8*)&stg[row*STG_ST + c + j*8];
  }
  __syncthreads();
  {
    int col0 = w * 32;
    #pragma unroll
    for(int rt=0;rt<4;++rt)
      #pragma unroll
      for(int nt=0;nt<2;++nt)
        #pragma unroll
        for(int i=0;i<4;++i)
          stg[(rt*16 + lg*4 + i)*STG_ST + col0 + nt*16 + lr] = f2b(accV[rt][nt][i]);
  }
  __syncthreads();
  {
    int row = tid >> 3, c = (tid & 7)*32;
    #pragma unroll
    for(int j=0;j<4;++j)
      *(s16x8*)(vbuf + (size_t)(t0+row)*DTD + c + j*8) = *(const s16x8*)&stg[row*STG_ST + c + j*8];
  }
}

// ====== fused attention + output: one block per (b,qi), 192 blocks =========
__global__ void __launch_bounds__(256)
k_att_out(const float* __restrict__ qcls, const float* __restrict__ qbuf,
          const unsigned short* __restrict__ kcls, const unsigned short* __restrict__ vcls,
          const unsigned short* __restrict__ kbuf, const unsigned short* __restrict__ vbuf,
          const float* __restrict__ wo, float* __restrict__ out){
  __shared__ float q_s[DTD];
  __shared__ float sc[HH][257];
  __shared__ float ao[DTD];
  int t = threadIdx.x;
  int b = blockIdx.x / 3, qi = blockIdx.x - b*3;

  q_s[t] = (qi==0) ? qcls[t] : qbuf[(size_t)(b*2+qi-1)*DTD + t];
  __syncthreads();
  const float scale = 0.17677669529663687f;  // 1/sqrt(32)
  for(int kk=t; kk<257; kk+=256){
    const unsigned short* kr = (kk==0) ? kcls : (kbuf + (size_t)(b*256+kk-1)*DTD);
    float acc[HH];
    #pragma unroll
    for(int h=0;h<HH;++h) acc[h]=0.f;
    #pragma unroll
    for(int j=0;j<32;++j){
      s16x8 u = *(const s16x8*)(kr + j*8);
      float p = 0.f;
      #pragma unroll
      for(int m=0;m<8;++m) p += q_s[j*8+m]*b2f((unsigned short)u[m]);
      acc[j>>2] += p;
    }
    #pragma unroll
    for(int h=0;h<HH;++h) sc[h][kk] = acc[h]*scale;
  }
  __syncthreads();
  { // softmax: 4 waves x 2 heads
    int wv = t>>6, lane = t&63;
    #pragma unroll
    for(int j=0;j<2;++j){
      int h = wv*2 + j;
      float x0=sc[h][lane], x1=sc[h][lane+64], x2=sc[h][lane+128], x3=sc[h][lane+192];
      float x4 = (lane==0)? sc[h][256] : -1e30f;
      float m = fmaxf(fmaxf(fmaxf(x0,x1),fmaxf(x2,x3)),x4);
      #pragma unroll
      for(int off=32; off>0; off>>=1) m = fmaxf(m, __shfl_xor(m, off));
      float e0=expf(x0-m), e1=expf(x1-m), e2v=expf(x2-m), e3v=expf(x3-m);
      float e4=(lane==0)? expf(x4-m) : 0.f;
      float s = e0+e1+e2v+e3v+e4;
      #pragma unroll
      for(int off=32; off>0; off>>=1) s += __shfl_xor(s, off);
      float inv = 1.0f/s;
      sc[h][lane]=e0*inv; sc[h][lane+64]=e1*inv;
      sc[h][lane+128]=e2v*inv; sc[h][lane+192]=e3v*inv;
      if(lane==0) sc[h][256]=e4*inv;
    }
  }
  __syncthreads();
  { // PV: thread = (h,dd); kk=0 cls then 256 tokens (4 partial accums)
    int h = t>>5, dd = t&31;
    float a0 = sc[h][0]*b2f(vcls[h*32+dd]);
    float a1=0.f, a2=0.f, a3=0.f;
    const unsigned short* vb = vbuf + (size_t)b*256*DTD + h*32 + dd;
    for(int kk=1; kk<257; kk+=4){
      a0 += sc[h][kk]  *b2f(vb[(size_t)(kk-1)*DTD]);
      a1 += sc[h][kk+1]*b2f(vb[(size_t)(kk)*DTD]);
      a2 += sc[h][kk+2]*b2f(vb[(size_t)(kk+1)*DTD]);
      a3 += sc[h][kk+3]*b2f(vb[(size_t)(kk+2)*DTD]);
    }
    ao[t] = a0+a1+a2+a3;
  }
  __syncthreads();
  { // out row = ao @ wo
    float acc = 0.f;
    for(int d=0; d<DTD; ++d) acc += ao[d]*wo[d*DTD + t];
    int off = (qi==1)? 0 : ((qi==2)? DTD : 2*DTD);
    out[(size_t)b*768 + off + t] = acc;
  }
}

extern "C" void kernel_launch(void* const* d_in, const int* in_sizes, int n_in,
                              void* d_out, int out_size, void* d_ws, size_t ws_size,
                              hipStream_t stream){
  const float* x        = (const float*)d_in[0];
  const float* proj_w   = (const float*)d_in[1];
  const float* proj_b   = (const float*)d_in[2];
  const float* adj_vals = (const float*)d_in[3];
  const int*   adj_rows = (const int*)d_in[4];
  const int*   adj_cols = (const int*)d_in[5];
  const float* ppr      = (const float*)d_in[6];
  const float* drnl     = (const float*)d_in[7];
  const int*   srcI     = (const int*)d_in[8];
  const int*   dstI     = (const int*)d_in[9];
  const int*   node_idx   = (const int*)d_in[11];
  const float* enc_w1   = (const float*)d_in[12];
  const float* enc_b1   = (const float*)d_in[13];
  const float* enc_w2   = (const float*)d_in[14];
  const float* enc_b2   = (const float*)d_in[15];
  const float* sw1      = (const float*)d_in[16];
  const float* sb1      = (const float*)d_in[17];
  const float* sw2      = (const float*)d_in[18];
  const float* sb2      = (const float*)d_in[19];
  const float* cls_tok  = (const float*)d_in[20];
  const float* wq       = (const float*)d_in[21];
  const float* wk       = (const float*)d_in[22];
  const float* wv       = (const float*)d_in[23];
  const float* wo       = (const float*)d_in[24];
  float* out = (float*)d_out;

  char* p = (char*)d_ws;
  auto alloc = [&](size_t bytes)->void*{ void* r = (void*)p; p += (bytes + 63) & ~(size_t)63; return r; };
  unsigned short* featsb = (unsigned short*)alloc((size_t)NN*DD*2);
  unsigned short* h1b    = (unsigned short*)alloc((size_t)NN*DD*2);
  unsigned short* h2b    = (unsigned short*)alloc((size_t)NN*DD*2);
  unsigned short* rexb   = (unsigned short*)alloc((size_t)NN*DD*2);
  int*   cnt     = (int*)  alloc((size_t)NN*4);
  uint2* ccv     = (uint2*)alloc((size_t)NN*CAP*8);
  float* sbias   = (float*)alloc((size_t)DD*4);
  float* heurA   = (float*)alloc((size_t)NTOK*4);
  float* heurB   = (float*)alloc((size_t)NTOK*4);
  float* heurD   = (float*)alloc((size_t)NTOK*4);
  unsigned short* kbuf = (unsigned short*)alloc((size_t)NTOK*DTD*2);
  unsigned short* vbuf = (unsigned short*)alloc((size_t)NTOK*DTD*2);
  float* qbuf    = (float*)alloc((size_t)BB*2*DTD*4);
  float* qcls    = (float*)alloc((size_t)DTD*4);
  unsigned short* kcls = (unsigned short*)alloc((size_t)DTD*2);
  unsigned short* vcls = (unsigned short*)alloc((size_t)DTD*2);
  unsigned short* wqT   = (unsigned short*)alloc((size_t)DTD*DTD*2);
  unsigned short* wkT   = (unsigned short*)alloc((size_t)DTD*DTD*2);
  unsigned short* wvT   = (unsigned short*)alloc((size_t)DTD*DTD*2);
  unsigned short* w2T2  = (unsigned short*)alloc((size_t)DD*DD*2);
  unsigned short* w2T3  = (unsigned short*)alloc((size_t)DD*DD*2);
  unsigned short* sw1aT = (unsigned short*)alloc((size_t)DD*DD*2);
  unsigned short* sw1bT = (unsigned short*)alloc((size_t)DD*DD*2);
  unsigned short* sw2T  = (unsigned short*)alloc((size_t)DD*DD*2);

  hipMemsetAsync(cnt, 0, NN*sizeof(int), stream);

  k_setup  <<<SETUP_GRID, 256, 0, stream>>>(x, proj_w, proj_b, featsb,
                                            wq, wk, wv, enc_w2, sw1, sw2, cls_tok,
                                            wqT, wkT, wvT, w2T2, w2T3, sw1aT, sw1bT, sw2T,
                                            node_idx, srcI, dstI, ppr, drnl,
                                            heurA, heurB, heurD,
                                            adj_rows, adj_cols, adj_vals, cnt, ccv,
                                            enc_b1, enc_b2, sb1, sbias,
                                            qcls, kcls, vcls);
  k_spmm_w <<<NN/4,   256, 0, stream>>>((const unsigned*)featsb, (unsigned*)h1b, cnt, ccv, (const unsigned*)featsb, 0);
  k_spmm_w <<<NN/4,   256, 0, stream>>>((const unsigned*)h1b, (unsigned*)h2b, cnt, ccv, (const unsigned*)featsb, 0);
  k_spmm_w <<<NN/4,   256, 0, stream>>>((const unsigned*)h2b, (unsigned*)rexb, cnt, ccv, (const unsigned*)featsb, 1);
  k_tok_kv <<<NTOK/64, 512, 0, stream>>>(node_idx, heurA, heurB, heurD,
                                         enc_w1, enc_b1, w2T2, w2T3, enc_b2,
                                         sw1aT, sw1bT, sbias, sw2T, sb2, rexb,
                                         wkT, wvT, wqT, kbuf, vbuf, qbuf);
  k_att_out<<<BB*3,    256, 0, stream>>>(qcls, qbuf, kcls, vcls, kbuf, vbuf, wo, out);
}